// Round 3
// baseline (2580.305 us; speedup 1.0000x reference)
//
#include <hip/hip_runtime.h>

#define NPTS 200000
#define NP2  200064          // padded row count (multiple of 128)
#define CIN 128
#define COUT 256
#define TAPS 62              // Wm[k] == 0 for k >= 62 (mask in setup) -> skip exactly
#define KNE 125

typedef __attribute__((ext_vector_type(8))) short bf16x8;    // 8 bf16 in 4 VGPRs
typedef __attribute__((ext_vector_type(4))) float f32x4;
typedef __attribute__((ext_vector_type(16))) float f32x16;

static __device__ __forceinline__ unsigned short f2bf(float f) {
    unsigned int u = __builtin_bit_cast(unsigned int, f);
    u = (u + 0x7fffu + ((u >> 16) & 1u)) >> 16;   // RNE
    return (unsigned short)u;
}

static __device__ __forceinline__ bf16x8 ld8(const unsigned short* p) {
    return *reinterpret_cast<const bf16x8*>(p);
}

// async global->LDS, 16B per lane. LDS dest = wave-uniform base + lane*16.
static __device__ __forceinline__ void gload_lds16(const void* g, void* l) {
    __builtin_amdgcn_global_load_lds(
        (const __attribute__((address_space(1))) unsigned int*)g,
        (__attribute__((address_space(3))) unsigned int*)l, 16, 0, 0);
}

// ---------------- prep: feats f32 -> bf16, plus zero row at index NPTS ----------------
__global__ void k_cast_feats(const float* __restrict__ src, unsigned short* __restrict__ dst) {
    const long long total4 = (long long)(NPTS + 1) * CIN / 4;
    for (long long i = (long long)blockIdx.x * blockDim.x + threadIdx.x; i < total4;
         i += (long long)gridDim.x * blockDim.x) {
        long long e = i * 4;
        float4 v = make_float4(0.f, 0.f, 0.f, 0.f);
        if (e < (long long)NPTS * CIN) v = *reinterpret_cast<const float4*>(src + e);
        ushort4 u;
        u.x = f2bf(v.x); u.y = f2bf(v.y); u.z = f2bf(v.z); u.w = f2bf(v.w);
        *reinterpret_cast<ushort4*>(dst + e) = u;
    }
}

// ---------------- prep: transpose + cast: dst[b][c][r] = (bf16) src[b][r][c] ----------------
__global__ void k_transpose_cast(const float* __restrict__ src, unsigned short* __restrict__ dst,
                                 int R, int C) {
    __shared__ float tile[64][65];
    const float* s = src + (long long)blockIdx.z * R * C;
    unsigned short* d = dst + (long long)blockIdx.z * R * C;
    const int r0 = blockIdx.x * 64, c0 = blockIdx.y * 64;
    const int tid = threadIdx.x;
#pragma unroll
    for (int i = 0; i < 16; ++i) {
        int e = i * 256 + tid;
        int rr = e >> 6, cc = e & 63;
        tile[rr][cc] = s[(long long)(r0 + rr) * C + (c0 + cc)];
    }
    __syncthreads();
#pragma unroll
    for (int i = 0; i < 16; ++i) {
        int e = i * 256 + tid;
        int orr = e >> 6, occ = e & 63;
        d[(long long)(c0 + orr) * R + (r0 + occ)] = f2bf(tile[occ][orr]);
    }
}

// ---------------- ctx GEMM: ctx[n] = bm + sum_t feats_b[nidx[n,t]] @ WmT[t] ----------------
// 512 thr (8 waves, 2M x 4N), block tile 128M x 256N, wave tile 64x64 of 32x32x16 MFMA.
// Per-tap order (sched_barrier-fenced): [16 B global loads (OLDEST)] ->
// [stage tap t+2 via gathered gload_lds + idx prefetch t+3 (NEWER)] -> [compute].
// In-order vmcnt: MFMA's B-wait never blocks on the gathers; gathers get ~2 taps of
// slack via 3-buffer LDS rotation + raw s_barrier (no vmcnt(0) drain).
// Safety induction: wave's B(t) vmcnt-wait forces its stage(t+1) (issued earlier)
// complete before barrier(t); all waves pass barrier(t) before reading buf(t+1).
__global__ __launch_bounds__(512, 2) void k_ctx(
    const unsigned short* __restrict__ feats_b,   // (NPTS+1) x 128
    const int* __restrict__ nidx,                 // NPTS x 125
    const unsigned short* __restrict__ wmt,       // 62 x 256(cout) x 128(cin)
    const float* __restrict__ bm,                 // 256
    unsigned short* __restrict__ ctx_b)           // NP2 x 256 (bf16)
{
    __shared__ unsigned short albuf[3][128 * 128];   // 3 x 32KB

    const int m0 = blockIdx.x * 128;
    const int lane = threadIdx.x & 63;
    const int w = threadIdx.x >> 6;
    const int wr = w >> 2, wc = w & 3;          // 2M x 4N
    const int wmL = wr * 64;
    const int wn0 = wc * 64;
    const int l31 = lane & 31, lh = lane >> 5;
    const int l15 = lane & 15, lk = lane >> 4;

    f32x16 acc[2][2] = {};

    // --- staging geometry: wave w stages rows w*16 .. w*16+15 (4 gloads, 4 rows each).
    // gload i: lane -> row i*4 + lk, 16B unit l15. Source pre-swizzled: unit l15 ^ (row&7).
    long long nbase[4];
    bool valid[4];
    int soff[4];            // swizzled source element offset within row
    int idxv[4];
#pragma unroll
    for (int i = 0; i < 4; ++i) {
        int rowg = m0 + w * 16 + i * 4 + lk;
        valid[i] = rowg < NPTS;
        nbase[i] = (long long)(valid[i] ? rowg : 0) * KNE;
        soff[i] = (l15 ^ ((i * 4 + lk) & 7)) << 3;
    }

    // --- A ds_read bases: row_l per mi, swizzled unit = (ks*2+lh) ^ (row_l&7)
    int arow[2], axor[2];
#pragma unroll
    for (int mi = 0; mi < 2; ++mi) {
        int row_l = wmL + mi * 32 + l31;
        arow[mi] = row_l * 128;
        axor[mi] = row_l & 7;
    }
    // --- B global base (elements): col*128 + lh*8
    int bb[2];
#pragma unroll
    for (int ni = 0; ni < 2; ++ni) bb[ni] = (wn0 + ni * 32 + l31) * 128 + lh * 8;

    unsigned short* bc = albuf[0];
    unsigned short* b1 = albuf[1];
    unsigned short* b2 = albuf[2];

    // --- prologue: stage taps 0,1; preload idx for tap 2; full drain + barrier
#pragma unroll
    for (int i = 0; i < 4; ++i) idxv[i] = valid[i] ? nidx[nbase[i] + 0] : NPTS;
#pragma unroll
    for (int i = 0; i < 4; ++i)
        gload_lds16(feats_b + (long long)(unsigned)idxv[i] * 128 + soff[i],
                    bc + (w * 16 + i * 4) * 128);
#pragma unroll
    for (int i = 0; i < 4; ++i) idxv[i] = valid[i] ? nidx[nbase[i] + 1] : NPTS;
#pragma unroll
    for (int i = 0; i < 4; ++i)
        gload_lds16(feats_b + (long long)(unsigned)idxv[i] * 128 + soff[i],
                    b1 + (w * 16 + i * 4) * 128);
#pragma unroll
    for (int i = 0; i < 4; ++i) idxv[i] = valid[i] ? nidx[nbase[i] + 2] : NPTS;
    __syncthreads();   // drains vmcnt(0): taps 0,1 staged for all waves

    for (int t = 0; t < TAPS; ++t) {
        const unsigned short* wt = wmt + (long long)t * (256 * 128);
        // 1) all B fragments for tap t — OLDEST vmem ops this iteration
        bf16x8 breg[2][8];
#pragma unroll
        for (int ni = 0; ni < 2; ++ni)
#pragma unroll
            for (int ks = 0; ks < 8; ++ks)
                breg[ni][ks] = ld8(wt + bb[ni] + ks * 16);
        __builtin_amdgcn_sched_barrier(0);
        // 2) stage tap t+2 (gathered) + idx prefetch for t+3 — NEWER, drained lazily
        if (t + 2 < TAPS) {
#pragma unroll
            for (int i = 0; i < 4; ++i)
                gload_lds16(feats_b + (long long)(unsigned)idxv[i] * 128 + soff[i],
                            b2 + (w * 16 + i * 4) * 128);
            const int tn = (t + 3 < TAPS) ? t + 3 : 0;
#pragma unroll
            for (int i = 0; i < 4; ++i) idxv[i] = valid[i] ? nidx[nbase[i] + tn] : NPTS;
        }
        __builtin_amdgcn_sched_barrier(0);
        // 3) compute tap t from bc
#pragma unroll
        for (int ks = 0; ks < 8; ++ks) {
            bf16x8 a0 = *reinterpret_cast<const bf16x8*>(
                bc + arow[0] + (((ks * 2 + lh) ^ axor[0]) << 3));
            bf16x8 a1 = *reinterpret_cast<const bf16x8*>(
                bc + arow[1] + (((ks * 2 + lh) ^ axor[1]) << 3));
            acc[0][0] = __builtin_amdgcn_mfma_f32_32x32x16_bf16(a0, breg[0][ks], acc[0][0], 0, 0, 0);
            acc[0][1] = __builtin_amdgcn_mfma_f32_32x32x16_bf16(a0, breg[1][ks], acc[0][1], 0, 0, 0);
            acc[1][0] = __builtin_amdgcn_mfma_f32_32x32x16_bf16(a1, breg[0][ks], acc[1][0], 0, 0, 0);
            acc[1][1] = __builtin_amdgcn_mfma_f32_32x32x16_bf16(a1, breg[1][ks], acc[1][1], 0, 0, 0);
        }
        __builtin_amdgcn_sched_barrier(0);
        __builtin_amdgcn_s_barrier();     // raw barrier: NO vmcnt(0) drain
        __builtin_amdgcn_sched_barrier(0);
        // rotate buffers
        unsigned short* tmp = bc; bc = b1; b1 = b2; b2 = tmp;
    }

    // epilogue: + bm, store bf16.  32x32 C/D: col=lane&31, row=(r&3)+8*(r>>2)+4*(lane>>5)
#pragma unroll
    for (int ni = 0; ni < 2; ++ni) {
        const int col = wn0 + ni * 32 + l31;
        const float bias = bm[col];
#pragma unroll
        for (int mi = 0; mi < 2; ++mi) {
#pragma unroll
            for (int r = 0; r < 16; ++r) {
                int row_l = (r & 3) + 8 * (r >> 2) + 4 * lh;
                int gr = m0 + wmL + mi * 32 + row_l;
                ctx_b[(long long)gr * 256 + col] = f2bf(acc[mi][ni][r] + bias);
            }
        }
    }
}

// ---------------- MLP: out = (relu(relu(ctx@W0+b0)@W1+b1))@W2+b2 ; split loc / |scale| ----------------
__global__ __launch_bounds__(512) void k_mlp(
    const unsigned short* __restrict__ ctx_b,
    const unsigned short* __restrict__ w0t, const float* __restrict__ b0,
    const unsigned short* __restrict__ w1t, const float* __restrict__ b1,
    const unsigned short* __restrict__ w2t, const float* __restrict__ b2,
    float* __restrict__ out)
{
    __shared__ unsigned short hbuf[128 * 256];
    const int m0 = blockIdx.x * 128;
    const int lane = threadIdx.x & 63;
    const int w = threadIdx.x >> 6;
    const int wr = w >> 2, wc = w & 3;
    const int l15 = lane & 15, lk = lane >> 4;
    const int wn0 = wc * 64;
    const int lm0 = wr * 64;
    const int wm0 = m0 + lm0;

    f32x4 acc[4][4];

    // ---- layer 1: A = ctx_b (global), B = w0t
#pragma unroll
    for (int i = 0; i < 4; ++i)
#pragma unroll
        for (int j = 0; j < 4; ++j) acc[i][j] = (f32x4){0.f, 0.f, 0.f, 0.f};
#pragma unroll
    for (int ks = 0; ks < 8; ++ks) {
        bf16x8 a[4], b[4];
#pragma unroll
        for (int mf = 0; mf < 4; ++mf)
            a[mf] = ld8(ctx_b + (long long)(wm0 + mf * 16 + l15) * 256 + lk * 8 + ks * 32);
#pragma unroll
        for (int nf = 0; nf < 4; ++nf)
            b[nf] = ld8(w0t + (wn0 + nf * 16 + l15) * 256 + lk * 8 + ks * 32);
#pragma unroll
        for (int mf = 0; mf < 4; ++mf)
#pragma unroll
            for (int nf = 0; nf < 4; ++nf)
                acc[mf][nf] = __builtin_amdgcn_mfma_f32_16x16x32_bf16(a[mf], b[nf], acc[mf][nf], 0, 0, 0);
    }
#pragma unroll
    for (int nf = 0; nf < 4; ++nf) {
        int col = wn0 + nf * 16 + l15;
        float bias = b0[col];
#pragma unroll
        for (int mf = 0; mf < 4; ++mf)
#pragma unroll
            for (int j = 0; j < 4; ++j) {
                int lr = lm0 + mf * 16 + lk * 4 + j;
                float v = fmaxf(acc[mf][nf][j] + bias, 0.f);
                int e = (lr * 256 + col) ^ ((lr & 7) << 3);
                hbuf[e] = f2bf(v);
            }
    }
    __syncthreads();

    // ---- layer 2: A = hbuf (swizzled), B = w1t
#pragma unroll
    for (int i = 0; i < 4; ++i)
#pragma unroll
        for (int j = 0; j < 4; ++j) acc[i][j] = (f32x4){0.f, 0.f, 0.f, 0.f};
#pragma unroll
    for (int ks = 0; ks < 8; ++ks) {
        bf16x8 a[4], b[4];
#pragma unroll
        for (int mf = 0; mf < 4; ++mf) {
            int lr = lm0 + mf * 16 + l15;
            int e = (lr * 256 + lk * 8 + ks * 32) ^ ((lr & 7) << 3);
            a[mf] = ld8(hbuf + e);
        }
#pragma unroll
        for (int nf = 0; nf < 4; ++nf)
            b[nf] = ld8(w1t + (wn0 + nf * 16 + l15) * 256 + lk * 8 + ks * 32);
#pragma unroll
        for (int mf = 0; mf < 4; ++mf)
#pragma unroll
            for (int nf = 0; nf < 4; ++nf)
                acc[mf][nf] = __builtin_amdgcn_mfma_f32_16x16x32_bf16(a[mf], b[nf], acc[mf][nf], 0, 0, 0);
    }
    __syncthreads();
#pragma unroll
    for (int nf = 0; nf < 4; ++nf) {
        int col = wn0 + nf * 16 + l15;
        float bias = b1[col];
#pragma unroll
        for (int mf = 0; mf < 4; ++mf)
#pragma unroll
            for (int j = 0; j < 4; ++j) {
                int lr = lm0 + mf * 16 + lk * 4 + j;
                float v = fmaxf(acc[mf][nf][j] + bias, 0.f);
                int e = (lr * 256 + col) ^ ((lr & 7) << 3);
                hbuf[e] = f2bf(v);
            }
    }
    __syncthreads();

    // ---- layer 3: A = hbuf, B = w2t, write outputs
#pragma unroll
    for (int i = 0; i < 4; ++i)
#pragma unroll
        for (int j = 0; j < 4; ++j) acc[i][j] = (f32x4){0.f, 0.f, 0.f, 0.f};
#pragma unroll
    for (int ks = 0; ks < 8; ++ks) {
        bf16x8 a[4], b[4];
#pragma unroll
        for (int mf = 0; mf < 4; ++mf) {
            int lr = lm0 + mf * 16 + l15;
            int e = (lr * 256 + lk * 8 + ks * 32) ^ ((lr & 7) << 3);
            a[mf] = ld8(hbuf + e);
        }
#pragma unroll
        for (int nf = 0; nf < 4; ++nf)
            b[nf] = ld8(w2t + (wn0 + nf * 16 + l15) * 256 + lk * 8 + ks * 32);
#pragma unroll
        for (int mf = 0; mf < 4; ++mf)
#pragma unroll
            for (int nf = 0; nf < 4; ++nf)
                acc[mf][nf] = __builtin_amdgcn_mfma_f32_16x16x32_bf16(a[mf], b[nf], acc[mf][nf], 0, 0, 0);
    }
#pragma unroll
    for (int nf = 0; nf < 4; ++nf) {
        int col = wn0 + nf * 16 + l15;
        float bias = b2[col];
#pragma unroll
        for (int mf = 0; mf < 4; ++mf)
#pragma unroll
            for (int j = 0; j < 4; ++j) {
                int gr = wm0 + mf * 16 + lk * 4 + j;
                if (gr < NPTS) {
                    float v = acc[mf][nf][j] + bias;
                    if (col < 128) out[(long long)gr * 128 + col] = v;
                    else out[(long long)NPTS * 128 + (long long)gr * 128 + (col - 128)] = fabsf(v);
                }
            }
    }
}

extern "C" void kernel_launch(void* const* d_in, const int* in_sizes, int n_in,
                              void* d_out, int out_size, void* d_ws, size_t ws_size,
                              hipStream_t stream) {
    const float* feats = (const float*)d_in[0];
    const int*   nidx  = (const int*)d_in[1];
    const float* Wm    = (const float*)d_in[2];
    const float* bm    = (const float*)d_in[3];
    const float* W0    = (const float*)d_in[4];
    const float* b0    = (const float*)d_in[5];
    const float* W1    = (const float*)d_in[6];
    const float* b1    = (const float*)d_in[7];
    const float* W2    = (const float*)d_in[8];
    const float* b2    = (const float*)d_in[9];

    char* ws = (char*)d_ws;
    size_t o = 0;
    unsigned short* feats_b = (unsigned short*)(ws + o); o += (size_t)(NPTS + 1) * CIN * 2;
    o = (o + 255) & ~(size_t)255;
    unsigned short* wmt = (unsigned short*)(ws + o); o += (size_t)TAPS * 256 * 128 * 2;
    unsigned short* w0t = (unsigned short*)(ws + o); o += 256 * 256 * 2;
    unsigned short* w1t = (unsigned short*)(ws + o); o += 256 * 256 * 2;
    unsigned short* w2t = (unsigned short*)(ws + o); o += 256 * 256 * 2;
    unsigned short* ctx_b = (unsigned short*)(ws + o); o += (size_t)NP2 * 256 * 2;

    k_cast_feats<<<2048, 256, 0, stream>>>(feats, feats_b);
    k_transpose_cast<<<dim3(2, 4, TAPS), 256, 0, stream>>>(Wm, wmt, 128, 256);
    k_transpose_cast<<<dim3(4, 4, 1), 256, 0, stream>>>(W0, w0t, 256, 256);
    k_transpose_cast<<<dim3(4, 4, 1), 256, 0, stream>>>(W1, w1t, 256, 256);
    k_transpose_cast<<<dim3(4, 4, 1), 256, 0, stream>>>(W2, w2t, 256, 256);
    k_ctx<<<NP2 / 128, 512, 0, stream>>>(feats_b, nidx, wmt, bm, ctx_b);
    k_mlp<<<NP2 / 128, 512, 0, stream>>>(ctx_b, w0t, b0, w1t, b1, w2t, b2, (float*)d_out);
}

// Round 5
// 1616.784 us; speedup vs baseline: 1.5959x; 1.5959x over previous
//
#include <hip/hip_runtime.h>

#define NPTS 200000
#define NP2  200064          // padded row count (multiple of 128)
#define CIN 128
#define COUT 256
#define TAPS 62              // Wm[k] == 0 for k >= 62 (mask in setup) -> skip exactly
#define KNE 125

typedef __attribute__((ext_vector_type(8))) short bf16x8;    // 8 bf16 in 4 VGPRs
typedef __attribute__((ext_vector_type(4))) float f32x4;
typedef __attribute__((ext_vector_type(16))) float f32x16;

static __device__ __forceinline__ unsigned short f2bf(float f) {
    unsigned int u = __builtin_bit_cast(unsigned int, f);
    u = (u + 0x7fffu + ((u >> 16) & 1u)) >> 16;   // RNE
    return (unsigned short)u;
}

static __device__ __forceinline__ bf16x8 ld8(const unsigned short* p) {
    return *reinterpret_cast<const bf16x8*>(p);
}

// async global->LDS, 16B per lane. LDS dest = wave-uniform base + lane*16.
static __device__ __forceinline__ void gload_lds16(const void* g, void* l) {
    __builtin_amdgcn_global_load_lds(
        (const __attribute__((address_space(1))) unsigned int*)g,
        (__attribute__((address_space(3))) unsigned int*)l, 16, 0, 0);
}

// ---------------- prep: feats f32 -> bf16, plus zero row at index NPTS ----------------
__global__ void k_cast_feats(const float* __restrict__ src, unsigned short* __restrict__ dst) {
    const long long total4 = (long long)(NPTS + 1) * CIN / 4;
    for (long long i = (long long)blockIdx.x * blockDim.x + threadIdx.x; i < total4;
         i += (long long)gridDim.x * blockDim.x) {
        long long e = i * 4;
        float4 v = make_float4(0.f, 0.f, 0.f, 0.f);
        if (e < (long long)NPTS * CIN) v = *reinterpret_cast<const float4*>(src + e);
        ushort4 u;
        u.x = f2bf(v.x); u.y = f2bf(v.y); u.z = f2bf(v.z); u.w = f2bf(v.w);
        *reinterpret_cast<ushort4*>(dst + e) = u;
    }
}

// ---------------- prep: transpose + cast: dst[b][c][r] = (bf16) src[b][r][c] ----------------
__global__ void k_transpose_cast(const float* __restrict__ src, unsigned short* __restrict__ dst,
                                 int R, int C) {
    __shared__ float tile[64][65];
    const float* s = src + (long long)blockIdx.z * R * C;
    unsigned short* d = dst + (long long)blockIdx.z * R * C;
    const int r0 = blockIdx.x * 64, c0 = blockIdx.y * 64;
    const int tid = threadIdx.x;
#pragma unroll
    for (int i = 0; i < 16; ++i) {
        int e = i * 256 + tid;
        int rr = e >> 6, cc = e & 63;
        tile[rr][cc] = s[(long long)(r0 + rr) * C + (c0 + cc)];
    }
    __syncthreads();
#pragma unroll
    for (int i = 0; i < 16; ++i) {
        int e = i * 256 + tid;
        int orr = e >> 6, occ = e & 63;
        d[(long long)(c0 + orr) * R + (r0 + occ)] = f2bf(tile[occ][orr]);
    }
}

// ---------------- ctx GEMM: ctx[n] = bm + sum_t feats_b[nidx[n,t]] @ WmT[t] ----------------
// 1024 thr (16 waves, 4M x 4N), block tile 256M x 256N, wave tile 64x64 of 32x32x16 MFMA.
// BOTH A (gathered rows) and B (wmt tap slice) staged into LDS via source-swizzled
// global_load_lds (rule 21: linear LDS dest, swizzled global source, swizzled read).
// Swizzle: 16B-unit u -> u ^ (row & 15)  => 2-way bank conflicts only (free).
// B staged ONCE per 256 rows -> B LLC traffic 3.1GB (was 12.4GB); A-gather 3.17GB no dup.
// Single-buffered A+B (128KB LDS), 2 syncthreads per tap: [compute][bar][stage][bar].
__global__ __launch_bounds__(1024, 4) void k_ctx(
    const unsigned short* __restrict__ feats_b,   // (NPTS+1) x 128
    const int* __restrict__ nidx,                 // NPTS x 125
    const unsigned short* __restrict__ wmt,       // 62 x 256(cout) x 128(cin)
    const float* __restrict__ bm,                 // 256
    unsigned short* __restrict__ ctx_b)           // NP2 x 256 (bf16)
{
    __shared__ unsigned short As[256 * 128];      // 64KB: A rows (swizzled units)
    __shared__ unsigned short Bs[256 * 128];      // 64KB: B cols (swizzled units)

    const int m0 = blockIdx.x * 256;
    const int lane = threadIdx.x & 63;
    const int w = threadIdx.x >> 6;               // 0..15
    const int wr = w >> 2, wc = w & 3;            // 4M x 4N
    const int wmL = wr * 64;                      // local M base of wave
    const int wn0 = wc * 64;                      // N base of wave
    const int l31 = lane & 31, lh = lane >> 5;
    const int l15 = lane & 15, lk = lane >> 4;

    f32x16 acc[2][2] = {};

    // --- staging geometry: wave w stages A rows w*16..w*16+15 and B cols w*16..w*16+15.
    // gload i (i=0..3): lane -> subrow sr = i*4 + lk, 16B unit l15.
    // source unit pre-swizzled: l15 ^ (sr) since (w*16+sr)&15 == sr.
    int srcel[4];            // swizzled source element offset within a 128-elem row
    long long nb[4];         // nidx row base for A-row of gload i
    bool valid[4];
    int bsub[4];             // B source row (col) local index = w*16 + sr
    int idxv[4];
#pragma unroll
    for (int i = 0; i < 4; ++i) {
        const int sr = i * 4 + lk;                // 0..15
        const int gr = m0 + w * 16 + sr;          // global A row
        valid[i] = gr < NPTS;
        nb[i] = (long long)(valid[i] ? gr : 0) * KNE;
        srcel[i] = (l15 ^ sr) << 3;
        bsub[i] = w * 16 + sr;                    // B col staged by this lane
    }

    // --- read addressing (element offsets into As/Bs)
    int aoffE[2], axr[2], boffE[2], bxr[2];
#pragma unroll
    for (int mi = 0; mi < 2; ++mi) {
        const int r = wmL + mi * 32 + l31;
        aoffE[mi] = r * 128; axr[mi] = r & 15;
    }
#pragma unroll
    for (int ni = 0; ni < 2; ++ni) {
        const int c = wn0 + ni * 32 + l31;
        boffE[ni] = c * 128; bxr[ni] = c & 15;
    }

    // --- prologue: stage tap 0 (A+B), prefetch idx for tap 1
#pragma unroll
    for (int i = 0; i < 4; ++i) idxv[i] = valid[i] ? nidx[nb[i] + 0] : NPTS;
#pragma unroll
    for (int i = 0; i < 4; ++i)
        gload_lds16(feats_b + (long long)(unsigned)idxv[i] * 128 + srcel[i],
                    As + (w * 16 + i * 4) * 128);
    {
        const unsigned short* wt0 = wmt;
#pragma unroll
        for (int i = 0; i < 4; ++i)
            gload_lds16(wt0 + bsub[i] * 128 + srcel[i], Bs + (w * 16 + i * 4) * 128);
    }
#pragma unroll
    for (int i = 0; i < 4; ++i) idxv[i] = valid[i] ? nidx[nb[i] + 1] : NPTS;
    __syncthreads();   // vmcnt(0): tap 0 staged

    for (int t = 0; t < TAPS; ++t) {
        // ---- compute tap t from As/Bs
#pragma unroll
        for (int ks = 0; ks < 8; ++ks) {
            const int u = ks * 2 + lh;            // 16B-unit index along K (0..15)
            bf16x8 a0 = ld8(As + aoffE[0] + ((u ^ axr[0]) << 3));
            bf16x8 a1 = ld8(As + aoffE[1] + ((u ^ axr[1]) << 3));
            bf16x8 b0 = ld8(Bs + boffE[0] + ((u ^ bxr[0]) << 3));
            bf16x8 b1 = ld8(Bs + boffE[1] + ((u ^ bxr[1]) << 3));
            acc[0][0] = __builtin_amdgcn_mfma_f32_32x32x16_bf16(a0, b0, acc[0][0], 0, 0, 0);
            acc[0][1] = __builtin_amdgcn_mfma_f32_32x32x16_bf16(a0, b1, acc[0][1], 0, 0, 0);
            acc[1][0] = __builtin_amdgcn_mfma_f32_32x32x16_bf16(a1, b0, acc[1][0], 0, 0, 0);
            acc[1][1] = __builtin_amdgcn_mfma_f32_32x32x16_bf16(a1, b1, acc[1][1], 0, 0, 0);
        }
        __syncthreads();   // all reads of As/Bs complete (WAR for restage)

        // ---- stage tap t+1 (A gathered + B linear), prefetch idx for t+2
        if (t + 1 < TAPS) {
#pragma unroll
            for (int i = 0; i < 4; ++i)
                gload_lds16(feats_b + (long long)(unsigned)idxv[i] * 128 + srcel[i],
                            As + (w * 16 + i * 4) * 128);
            const unsigned short* wt = wmt + (long long)(t + 1) * (256 * 128);
#pragma unroll
            for (int i = 0; i < 4; ++i)
                gload_lds16(wt + bsub[i] * 128 + srcel[i], Bs + (w * 16 + i * 4) * 128);
            const int tn = (t + 2 < TAPS) ? t + 2 : 0;
#pragma unroll
            for (int i = 0; i < 4; ++i) idxv[i] = valid[i] ? nidx[nb[i] + tn] : NPTS;
            __syncthreads();   // vmcnt(0): tap t+1 staged for all waves
        }
    }

    // epilogue: + bm, store bf16.  32x32 C/D: col=lane&31, row=(r&3)+8*(r>>2)+4*(lane>>5)
#pragma unroll
    for (int ni = 0; ni < 2; ++ni) {
        const int col = wn0 + ni * 32 + l31;
        const float bias = bm[col];
#pragma unroll
        for (int mi = 0; mi < 2; ++mi) {
#pragma unroll
            for (int r = 0; r < 16; ++r) {
                int row_l = (r & 3) + 8 * (r >> 2) + 4 * lh;
                int gr = m0 + wmL + mi * 32 + row_l;
                if (gr < NP2) ctx_b[(long long)gr * 256 + col] = f2bf(acc[mi][ni][r] + bias);
            }
        }
    }
}

// ---------------- MLP: out = (relu(relu(ctx@W0+b0)@W1+b1))@W2+b2 ; split loc / |scale| ----------------
__global__ __launch_bounds__(512) void k_mlp(
    const unsigned short* __restrict__ ctx_b,
    const unsigned short* __restrict__ w0t, const float* __restrict__ b0,
    const unsigned short* __restrict__ w1t, const float* __restrict__ b1,
    const unsigned short* __restrict__ w2t, const float* __restrict__ b2,
    float* __restrict__ out)
{
    __shared__ unsigned short hbuf[128 * 256];
    const int m0 = blockIdx.x * 128;
    const int lane = threadIdx.x & 63;
    const int w = threadIdx.x >> 6;
    const int wr = w >> 2, wc = w & 3;
    const int l15 = lane & 15, lk = lane >> 4;
    const int wn0 = wc * 64;
    const int lm0 = wr * 64;
    const int wm0 = m0 + lm0;

    f32x4 acc[4][4];

    // ---- layer 1: A = ctx_b (global), B = w0t
#pragma unroll
    for (int i = 0; i < 4; ++i)
#pragma unroll
        for (int j = 0; j < 4; ++j) acc[i][j] = (f32x4){0.f, 0.f, 0.f, 0.f};
#pragma unroll
    for (int ks = 0; ks < 8; ++ks) {
        bf16x8 a[4], b[4];
#pragma unroll
        for (int mf = 0; mf < 4; ++mf)
            a[mf] = ld8(ctx_b + (long long)(wm0 + mf * 16 + l15) * 256 + lk * 8 + ks * 32);
#pragma unroll
        for (int nf = 0; nf < 4; ++nf)
            b[nf] = ld8(w0t + (wn0 + nf * 16 + l15) * 256 + lk * 8 + ks * 32);
#pragma unroll
        for (int mf = 0; mf < 4; ++mf)
#pragma unroll
            for (int nf = 0; nf < 4; ++nf)
                acc[mf][nf] = __builtin_amdgcn_mfma_f32_16x16x32_bf16(a[mf], b[nf], acc[mf][nf], 0, 0, 0);
    }
#pragma unroll
    for (int nf = 0; nf < 4; ++nf) {
        int col = wn0 + nf * 16 + l15;
        float bias = b0[col];
#pragma unroll
        for (int mf = 0; mf < 4; ++mf)
#pragma unroll
            for (int j = 0; j < 4; ++j) {
                int lr = lm0 + mf * 16 + lk * 4 + j;
                float v = fmaxf(acc[mf][nf][j] + bias, 0.f);
                int e = (lr * 256 + col) ^ ((lr & 7) << 3);
                hbuf[e] = f2bf(v);
            }
    }
    __syncthreads();

    // ---- layer 2: A = hbuf (swizzled), B = w1t
#pragma unroll
    for (int i = 0; i < 4; ++i)
#pragma unroll
        for (int j = 0; j < 4; ++j) acc[i][j] = (f32x4){0.f, 0.f, 0.f, 0.f};
#pragma unroll
    for (int ks = 0; ks < 8; ++ks) {
        bf16x8 a[4], b[4];
#pragma unroll
        for (int mf = 0; mf < 4; ++mf) {
            int lr = lm0 + mf * 16 + l15;
            int e = (lr * 256 + lk * 8 + ks * 32) ^ ((lr & 7) << 3);
            a[mf] = ld8(hbuf + e);
        }
#pragma unroll
        for (int nf = 0; nf < 4; ++nf)
            b[nf] = ld8(w1t + (wn0 + nf * 16 + l15) * 256 + lk * 8 + ks * 32);
#pragma unroll
        for (int mf = 0; mf < 4; ++mf)
#pragma unroll
            for (int nf = 0; nf < 4; ++nf)
                acc[mf][nf] = __builtin_amdgcn_mfma_f32_16x16x32_bf16(a[mf], b[nf], acc[mf][nf], 0, 0, 0);
    }
    __syncthreads();
#pragma unroll
    for (int nf = 0; nf < 4; ++nf) {
        int col = wn0 + nf * 16 + l15;
        float bias = b1[col];
#pragma unroll
        for (int mf = 0; mf < 4; ++mf)
#pragma unroll
            for (int j = 0; j < 4; ++j) {
                int lr = lm0 + mf * 16 + lk * 4 + j;
                float v = fmaxf(acc[mf][nf][j] + bias, 0.f);
                int e = (lr * 256 + col) ^ ((lr & 7) << 3);
                hbuf[e] = f2bf(v);
            }
    }
    __syncthreads();

    // ---- layer 3: A = hbuf, B = w2t, write outputs
#pragma unroll
    for (int i = 0; i < 4; ++i)
#pragma unroll
        for (int j = 0; j < 4; ++j) acc[i][j] = (f32x4){0.f, 0.f, 0.f, 0.f};
#pragma unroll
    for (int ks = 0; ks < 8; ++ks) {
        bf16x8 a[4], b[4];
#pragma unroll
        for (int mf = 0; mf < 4; ++mf) {
            int lr = lm0 + mf * 16 + l15;
            int e = (lr * 256 + lk * 8 + ks * 32) ^ ((lr & 7) << 3);
            a[mf] = ld8(hbuf + e);
        }
#pragma unroll
        for (int nf = 0; nf < 4; ++nf)
            b[nf] = ld8(w2t + (wn0 + nf * 16 + l15) * 256 + lk * 8 + ks * 32);
#pragma unroll
        for (int mf = 0; mf < 4; ++mf)
#pragma unroll
            for (int nf = 0; nf < 4; ++nf)
                acc[mf][nf] = __builtin_amdgcn_mfma_f32_16x16x32_bf16(a[mf], b[nf], acc[mf][nf], 0, 0, 0);
    }
#pragma unroll
    for (int nf = 0; nf < 4; ++nf) {
        int col = wn0 + nf * 16 + l15;
        float bias = b2[col];
#pragma unroll
        for (int mf = 0; mf < 4; ++mf)
#pragma unroll
            for (int j = 0; j < 4; ++j) {
                int gr = wm0 + mf * 16 + lk * 4 + j;
                if (gr < NPTS) {
                    float v = acc[mf][nf][j] + bias;
                    if (col < 128) out[(long long)gr * 128 + col] = v;
                    else out[(long long)NPTS * 128 + (long long)gr * 128 + (col - 128)] = fabsf(v);
                }
            }
    }
}

extern "C" void kernel_launch(void* const* d_in, const int* in_sizes, int n_in,
                              void* d_out, int out_size, void* d_ws, size_t ws_size,
                              hipStream_t stream) {
    const float* feats = (const float*)d_in[0];
    const int*   nidx  = (const int*)d_in[1];
    const float* Wm    = (const float*)d_in[2];
    const float* bm    = (const float*)d_in[3];
    const float* W0    = (const float*)d_in[4];
    const float* b0    = (const float*)d_in[5];
    const float* W1    = (const float*)d_in[6];
    const float* b1    = (const float*)d_in[7];
    const float* W2    = (const float*)d_in[8];
    const float* b2    = (const float*)d_in[9];

    char* ws = (char*)d_ws;
    size_t o = 0;
    unsigned short* feats_b = (unsigned short*)(ws + o); o += (size_t)(NPTS + 1) * CIN * 2;
    o = (o + 255) & ~(size_t)255;
    unsigned short* wmt = (unsigned short*)(ws + o); o += (size_t)TAPS * 256 * 128 * 2;
    unsigned short* w0t = (unsigned short*)(ws + o); o += 256 * 256 * 2;
    unsigned short* w1t = (unsigned short*)(ws + o); o += 256 * 256 * 2;
    unsigned short* w2t = (unsigned short*)(ws + o); o += 256 * 256 * 2;
    unsigned short* ctx_b = (unsigned short*)(ws + o); o += (size_t)NP2 * 256 * 2;

    k_cast_feats<<<2048, 256, 0, stream>>>(feats, feats_b);
    k_transpose_cast<<<dim3(2, 4, TAPS), 256, 0, stream>>>(Wm, wmt, 128, 256);
    k_transpose_cast<<<dim3(4, 4, 1), 256, 0, stream>>>(W0, w0t, 256, 256);
    k_transpose_cast<<<dim3(4, 4, 1), 256, 0, stream>>>(W1, w1t, 256, 256);
    k_transpose_cast<<<dim3(4, 4, 1), 256, 0, stream>>>(W2, w2t, 256, 256);
    k_ctx<<<(NP2 + 255) / 256, 1024, 0, stream>>>(feats_b, nidx, wmt, bm, ctx_b);
    k_mlp<<<NP2 / 128, 512, 0, stream>>>(ctx_b, w0t, b0, w1t, b1, w2t, b2, (float*)d_out);
}